// Round 9
// baseline (98.190 us; speedup 1.0000x reference)
//
#include <hip/hip_runtime.h>

#define NN 64
#define DD 32

__device__ __forceinline__ float sigmoidf_(float x) {
    return 1.0f / (1.0f + __expf(-x));
}

// read lane l's value of v (wave-uniform); lane l holds per-lane data for the wave
__device__ __forceinline__ float rlanef_(float v, int l) {
    return __int_as_float(__builtin_amdgcn_readlane(__float_as_int(v), l));
}

// ---------------------------------------------------------------------------
// FULLY FUSED kernel: one block per (b, q); block owns rows n = {q,q+16,q+32,q+48}
// for ALL t in [0,16). conv1d mixes only over t at fixed (n,d), so with all t
// in-block, h1 never leaves LDS and the 2-kernel pipeline becomes one node
// (measured: ~3 us/graph-node overhead; 15 nodes/iter, we controlled 2 -> 1).
//
// ROUND-8 FIX: previous version read sG0 (written by lanes 0-31) from lanes
// 32-63 of the same wave with no barrier -> uninitialized-LDS NaN risk (the
// only unproven ordering; bench showed absmax=nan). Now g0 lives in a
// REGISTER per lane and z0 uses v_readlane — no LDS RAW at all. Also fixed
// an OOB W1_0 staging read (160 > 128 elements).
//
// Audited algebra (same as round-5's measured-correct kernel):
//  * sigmoid monotone => reduce_pair(g2) = sigmoid(max/min_j preactivation)
//  * preact s[i,j,d] = A_i[d] + Bv_j[d] + (i<j?w2:w7) + (ni<nj?w4:w9), j!=i
//  * reduce_pair(cmp): ch0 -> (i<63),(i==0); ch1 -> 0; ch2: EC2=(ni<gmax),
//    AC2=(ni==gmin)  (distinct n values; gmax/gmin over all j)
//  * g0 folded into z0[t][d] (i-independent)
// ---------------------------------------------------------------------------
__global__ __launch_bounds__(1024) void fused_kernel(
    const float* __restrict__ x,
    const float* __restrict__ W1_0, const float* __restrict__ b1_0,
    const float* __restrict__ W1_1, const float* __restrict__ b1_1,
    const float* __restrict__ W1_2, const float* __restrict__ b1_2,
    const float* __restrict__ W2_1, const float* __restrict__ b2_1,
    const float* __restrict__ Wc,   const float* __restrict__ bc,
    float* __restrict__ out)
{
    __shared__ __align__(16) float sx0[16][64];
    __shared__ __align__(16) float sx1[16][64];
    __shared__ __align__(16) float sFeat[64][100];  // row r=t*4+m; 0..31 g1, 32..95 e/a
    __shared__ __align__(16) float sW2p[32][100];   // W2_1[d][32+kp]
    __shared__ __align__(16) float sW2a[32][33];    // W2_1[d][0..31], pad 33
    __shared__ __align__(16) float sH1[18][4][32];  // [t+1][m][d], rows 0/17 zero
    __shared__ float sW12[320], sB12[32];
    __shared__ float sW11t[256], sB11[32];          // [c][d]
    __shared__ float sW10[128], sB10[32], sB21[32];
    __shared__ float sZ0[16][32];

    const int tid = threadIdx.x;
    const int bq  = blockIdx.x;
    const int b   = bq >> 4;
    const int qn  = bq & 15;

    // ---------------- staging ----------------
    {
        int t = tid >> 6, j = tid & 63;
        float2 v = *(const float2*)&x[((b*16 + t)*64 + j)*2];
        sx0[t][j] = v.x; sx1[t][j] = v.y;
    }
    for (int idx = tid; idx < 32*96; idx += 1024) {
        int dr = idx / 96, kp = idx - dr*96;
        sW2p[dr][kp] = W2_1[dr*128 + 32 + kp];
    }
    {
        int dr = tid >> 5, k = tid & 31;
        sW2a[dr][k] = W2_1[dr*128 + k];
    }
    if (tid < 320) sW12[tid] = W1_2[tid];
    else if (tid < 352) sB12[tid-320] = b1_2[tid-320];
    else if (tid < 608) { int i2 = tid-352; sW11t[(i2&7)*32 + (i2>>3)] = W1_1[i2]; }
    else if (tid < 640) sB11[tid-608] = b1_1[tid-608];
    else if (tid < 768) sW10[tid-640] = W1_0[tid-640];       // exactly 128 elements
    else if (tid < 800) sB10[tid-768] = b1_0[tid-768];
    else if (tid < 832) sB21[tid-800] = b2_1[tid-800];
    if (tid < 128) { int m = (tid>>5)&3, dl = tid&31; sH1[0][m][dl] = 0.0f; sH1[17][m][dl] = 0.0f; }
    __syncthreads();

    // ---------------- phase 1: per-wave (one t each) ----------------
    {
        const int t    = tid >> 6;
        const int lane = tid & 63;
        const int mm   = lane >> 5;
        const int d    = lane & 31;

        const float myx0 = sx0[t][lane];
        const float myx1 = sx1[t][lane];

        // 64-lane butterfly stats (all-j, matches reduce_unary; gmax/gmin for EC2/AC2)
        float mx0 = myx0, mn0 = myx0, mx1 = myx1, mn1 = myx1;
        #pragma unroll
        for (int off = 1; off < 64; off <<= 1) {
            mx0 = fmaxf(mx0, __shfl_xor(mx0, off));
            mn0 = fminf(mn0, __shfl_xor(mn0, off));
            mx1 = fmaxf(mx1, __shfl_xor(mx1, off));
            mn1 = fminf(mn1, __shfl_xor(mn1, off));
        }
        // g0[d] in a REGISTER on every lane (lane d and d+32 hold the same value;
        // readlane below consumes lanes 0..31). No LDS hand-off -> no RAW hazard.
        const float g0reg = sigmoidf_(mx0*sW10[d*4+0] + mn0*sW10[d*4+1]
                                    + mx1*sW10[d*4+2] + mn1*sW10[d*4+3] + sB10[d]);
        // z0[d] = b2_1[d] + sum_k g0[k]*W2_1[d][k] via readlane (wave-uniform g0[k])
        {
            float z = sB21[d];
            #pragma unroll
            for (int k = 0; k < 32; ++k)
                z += rlanef_(g0reg, k) * sW2a[d][k];
            if (mm == 0) sZ0[t][d] = z;      // one write per (t,d); read after barrier
        }

        // W1_2 row for this d
        const float w0 = sW12[d*10+0], w1 = sW12[d*10+1], w2 = sW12[d*10+2],
                    w4 = sW12[d*10+4], w5 = sW12[d*10+5], w6 = sW12[d*10+6],
                    w7 = sW12[d*10+7], w9 = sW12[d*10+9];
        const float bw = sB12[d];

        const int ia = qn + (mm << 4);      // in [0,32)
        const int ib = ia + 32;             // in [32,64)
        const float na  = sx1[t][ia], xa0 = sx0[t][ia];
        const float nb  = sx1[t][ib], xb0 = sx0[t][ib];
        const float Aa = xa0*w0 + na*w1 + bw;
        const float Ab = xb0*w0 + nb*w1 + bw;
        const float A24a = Aa + w2 + w4, A29a = Aa + w2 + w9;
        const float A74a = Aa + w7 + w4, A79a = Aa + w7 + w9;
        const float A24b = Ab + w2 + w4, A29b = Ab + w2 + w9;
        const float A74b = Ab + w7 + w4, A79b = Ab + w7 + w9;
        float smaxa = -1e30f, smina = 1e30f;
        float smaxb = -1e30f, sminb = 1e30f;

        #pragma unroll
        for (int j = 0; j < 32; ++j) {          // j in [0,32): row b static (w7, no excl)
            const float x0j = rlanef_(myx0, j);
            const float x1j = rlanef_(myx1, j);
            const float bv  = x0j*w5 + x1j*w6;
            const float tb = ((nb < x1j) ? A74b : A79b) + bv;
            smaxb = fmaxf(smaxb, tb);
            sminb = fminf(sminb, tb);
            const bool ca = (na < x1j);
            const float t2 = ca ? A24a : A29a;
            const float t7 = ca ? A74a : A79a;
            const float ta = ((ia < j) ? t2 : t7) + bv;
            const bool va = (j != ia);
            smaxa = fmaxf(smaxa, va ? ta : -1e30f);
            smina = fminf(smina, va ? ta :  1e30f);
        }
        #pragma unroll
        for (int j = 32; j < 64; ++j) {         // j in [32,64): row a static (w2, no excl)
            const float x0j = rlanef_(myx0, j);
            const float x1j = rlanef_(myx1, j);
            const float bv  = x0j*w5 + x1j*w6;
            const float ta = ((na < x1j) ? A24a : A29a) + bv;
            smaxa = fmaxf(smaxa, ta);
            smina = fminf(smina, ta);
            const bool cb = (nb < x1j);
            const float t2 = cb ? A24b : A29b;
            const float t7 = cb ? A74b : A79b;
            const float tb = ((ib < j) ? t2 : t7) + bv;
            const bool vb = (j != ib);
            smaxb = fmaxf(smaxb, vb ? tb : -1e30f);
            sminb = fminf(sminb, vb ? tb :  1e30f);
        }
        const int ra = t*4 + mm;
        const int rb = ra + 2;
        *(float2*)&sFeat[ra][32 + 2*d] = make_float2(sigmoidf_(smaxa), sigmoidf_(smina));
        *(float2*)&sFeat[rb][32 + 2*d] = make_float2(sigmoidf_(smaxb), sigmoidf_(sminb));

        // g1: ch0 e=(i<63), a=(i==0); ch1 zero; ch2 via gmax/gmin
        float z1a = xa0*sW11t[0*32+d] + na*sW11t[1*32+d]
                  + sW11t[2*32+d]                          // ia <= 31 < 63 always
                  + ((ia == 0)   ? sW11t[3*32+d] : 0.0f)
                  + ((na < mx1)  ? sW11t[6*32+d] : 0.0f)
                  + ((na == mn1) ? sW11t[7*32+d] : 0.0f) + sB11[d];
        sFeat[ra][d] = sigmoidf_(z1a);
        float z1b = xb0*sW11t[0*32+d] + nb*sW11t[1*32+d]
                  + ((ib < 63)   ? sW11t[2*32+d] : 0.0f)   // ib==0 impossible
                  + ((nb < mx1)  ? sW11t[6*32+d] : 0.0f)
                  + ((nb == mn1) ? sW11t[7*32+d] : 0.0f) + sB11[d];
        sFeat[rb][d] = sigmoidf_(z1b);
    }
    __syncthreads();

    // issue conv pass-A weight loads + bias now: in flight during phase F
    const int dc = tid & 31;
    const float* wrow = Wc + dc*96;
    float4 wv0[12];
    #pragma unroll
    for (int c = 0; c < 12; ++c) wv0[c] = *(const float4*)(wrow + c*4);
    const float bcv = bc[dc];

    // ---------------- phase F: h1 = swish(sigmoid(z0 + feat . W2p)) ----------------
    if (tid < 512) {
        const int rp = tid >> 4;     // 0..31 -> rows rp, rp+32
        const int dh = tid & 15;     // cols dh, dh+16
        const float* fA = sFeat[rp];
        const float* fB = sFeat[rp+32];
        const float* wA = sW2p[dh];
        const float* wB = sW2p[dh+16];
        float a00 = sZ0[rp>>2][dh],     a01 = sZ0[rp>>2][dh+16];
        float a10 = sZ0[(rp>>2)+8][dh], a11 = sZ0[(rp>>2)+8][dh+16];
        #pragma unroll
        for (int kc = 0; kc < 96; kc += 4) {
            const float4 pa = *(const float4*)(wA + kc);
            const float4 pb = *(const float4*)(wB + kc);
            const float4 va = *(const float4*)(fA + kc);
            const float4 vb = *(const float4*)(fB + kc);
            a00 += va.x*pa.x + va.y*pa.y + va.z*pa.z + va.w*pa.w;
            a01 += va.x*pb.x + va.y*pb.y + va.z*pb.z + va.w*pb.w;
            a10 += vb.x*pa.x + vb.y*pa.y + vb.z*pa.z + vb.w*pa.w;
            a11 += vb.x*pb.x + vb.y*pb.y + vb.z*pb.z + vb.w*pb.w;
        }
        float h;
        h = sigmoidf_(a00); sH1[(rp>>2)+1][rp&3][dh]    = h * sigmoidf_(h);
        h = sigmoidf_(a01); sH1[(rp>>2)+1][rp&3][dh+16] = h * sigmoidf_(h);
        h = sigmoidf_(a10); sH1[(rp>>2)+9][rp&3][dh]    = h * sigmoidf_(h);
        h = sigmoidf_(a11); sH1[(rp>>2)+9][rp&3][dh+16] = h * sigmoidf_(h);
    }
    __syncthreads();

    // ---------------- conv1d over t (k=3, pad 1) + bias + swish ----------------
    {
        const int gg = tid >> 9;           // 0/1 -> outputs g = gg, gg+2
        const int tt = (tid >> 5) & 15;
        const int gQ = gg + 2;

        // unpack pass-A weights (k in [0,48)) to scalars (static idx -> regs)
        float wk[48];
        #pragma unroll
        for (int c = 0; c < 12; ++c) {
            wk[c*4+0] = wv0[c].x; wk[c*4+1] = wv0[c].y;
            wk[c*4+2] = wv0[c].z; wk[c*4+3] = wv0[c].w;
        }
        // issue pass-B loads (k in [48,96)) -> in flight during pass A
        float4 wv1[12];
        #pragma unroll
        for (int c = 0; c < 12; ++c) wv1[c] = *(const float4*)(wrow + 48 + c*4);

        float accP = bcv, accQ = bcv;
        #pragma unroll
        for (int c = 0; c < 4; ++c) {       // input channels i = c*4+e in [0,16)
            const int qk = c*12;
            float4 f0 = *(const float4*)&sH1[tt  ][gg][c*4];
            float4 f1 = *(const float4*)&sH1[tt+1][gg][c*4];
            float4 f2 = *(const float4*)&sH1[tt+2][gg][c*4];
            accP += f0.x*wk[qk+0] + f1.x*wk[qk+1]  + f2.x*wk[qk+2];
            accP += f0.y*wk[qk+3] + f1.y*wk[qk+4]  + f2.y*wk[qk+5];
            accP += f0.z*wk[qk+6] + f1.z*wk[qk+7]  + f2.z*wk[qk+8];
            accP += f0.w*wk[qk+9] + f1.w*wk[qk+10] + f2.w*wk[qk+11];
            f0 = *(const float4*)&sH1[tt  ][gQ][c*4];
            f1 = *(const float4*)&sH1[tt+1][gQ][c*4];
            f2 = *(const float4*)&sH1[tt+2][gQ][c*4];
            accQ += f0.x*wk[qk+0] + f1.x*wk[qk+1]  + f2.x*wk[qk+2];
            accQ += f0.y*wk[qk+3] + f1.y*wk[qk+4]  + f2.y*wk[qk+5];
            accQ += f0.z*wk[qk+6] + f1.z*wk[qk+7]  + f2.z*wk[qk+8];
            accQ += f0.w*wk[qk+9] + f1.w*wk[qk+10] + f2.w*wk[qk+11];
        }
        // pass B: unpack and finish
        float wkB[48];
        #pragma unroll
        for (int c = 0; c < 12; ++c) {
            wkB[c*4+0] = wv1[c].x; wkB[c*4+1] = wv1[c].y;
            wkB[c*4+2] = wv1[c].z; wkB[c*4+3] = wv1[c].w;
        }
        #pragma unroll
        for (int c = 4; c < 8; ++c) {       // input channels i in [16,32)
            const int qk = (c-4)*12;
            float4 f0 = *(const float4*)&sH1[tt  ][gg][c*4];
            float4 f1 = *(const float4*)&sH1[tt+1][gg][c*4];
            float4 f2 = *(const float4*)&sH1[tt+2][gg][c*4];
            accP += f0.x*wkB[qk+0] + f1.x*wkB[qk+1]  + f2.x*wkB[qk+2];
            accP += f0.y*wkB[qk+3] + f1.y*wkB[qk+4]  + f2.y*wkB[qk+5];
            accP += f0.z*wkB[qk+6] + f1.z*wkB[qk+7]  + f2.z*wkB[qk+8];
            accP += f0.w*wkB[qk+9] + f1.w*wkB[qk+10] + f2.w*wkB[qk+11];
            f0 = *(const float4*)&sH1[tt  ][gQ][c*4];
            f1 = *(const float4*)&sH1[tt+1][gQ][c*4];
            f2 = *(const float4*)&sH1[tt+2][gQ][c*4];
            accQ += f0.x*wkB[qk+0] + f1.x*wkB[qk+1]  + f2.x*wkB[qk+2];
            accQ += f0.y*wkB[qk+3] + f1.y*wkB[qk+4]  + f2.y*wkB[qk+5];
            accQ += f0.z*wkB[qk+6] + f1.z*wkB[qk+7]  + f2.z*wkB[qk+8];
            accQ += f0.w*wkB[qk+9] + f1.w*wkB[qk+10] + f2.w*wkB[qk+11];
        }
        out[((b*16 + tt)*64 + (qn + 16*gg))*32 + dc] = accP * sigmoidf_(accP);
        out[((b*16 + tt)*64 + (qn + 16*gQ))*32 + dc] = accQ * sigmoidf_(accQ);
    }
}

extern "C" void kernel_launch(void* const* d_in, const int* in_sizes, int n_in,
                              void* d_out, int out_size, void* d_ws, size_t ws_size,
                              hipStream_t stream) {
    const float* x    = (const float*)d_in[0];
    const float* W1_0 = (const float*)d_in[1];
    const float* b1_0 = (const float*)d_in[2];
    const float* W1_1 = (const float*)d_in[3];
    const float* b1_1 = (const float*)d_in[4];
    const float* W1_2 = (const float*)d_in[5];
    const float* b1_2 = (const float*)d_in[6];
    const float* W2_1 = (const float*)d_in[7];
    const float* b2_1 = (const float*)d_in[8];
    const float* Wc   = (const float*)d_in[9];
    const float* bc   = (const float*)d_in[10];

    fused_kernel<<<256, 1024, 0, stream>>>(x, W1_0, b1_0, W1_1, b1_1,
                                           W1_2, b1_2, W2_1, b2_1,
                                           Wc, bc, (float*)d_out);
}